// Round 1
// baseline (120.625 us; speedup 1.0000x reference)
//
#include <hip/hip_runtime.h>
#include <math.h>

#define NUM_CLASSES 80
#define REG_MAX 16
#define NCH 144            // 4*REG_MAX + NUM_CLASSES
#define A_TOT 8400         // 80*80 + 40*40 + 20*20
#define BATCH 32
#define MAX_DET 300
#define CONF_THR 0.25f
#define IOU_THR 0.7f
#define MAX_WH 7680.0f
#define CAND_CAP 2048
#define NBINS 1024
#define MASK_W 10          // ceil(300/32)

// ---------------------------------------------------------------------------
// Kernel 1: decode. One thread per (batch, anchor).
// Produces: boxes (xyxy, stride-scaled), thresholded sigmoid score, argmax cls.
// ---------------------------------------------------------------------------
__global__ __launch_bounds__(256) void decode_kernel(
    const float* __restrict__ p3, const float* __restrict__ p4,
    const float* __restrict__ p5,
    float* __restrict__ boxes, float* __restrict__ scores,
    int* __restrict__ clsArr)
{
    int t = blockIdx.x * blockDim.x + threadIdx.x;
    if (t >= BATCH * A_TOT) return;
    int b = t / A_TOT;
    int a = t - b * A_TOT;

    const float* src;
    float stride, gx, gy;
    if (a < 6400) {
        src = p3 + ((size_t)b * 6400 + a) * NCH;
        stride = 8.0f;
        int gyi = a / 80;                    // const divisor -> magic mul
        gx = (float)(a - gyi * 80) + 0.5f;
        gy = (float)gyi + 0.5f;
    } else if (a < 8000) {
        int i = a - 6400;
        src = p4 + ((size_t)b * 1600 + i) * NCH;
        stride = 16.0f;
        int gyi = i / 40;
        gx = (float)(i - gyi * 40) + 0.5f;
        gy = (float)gyi + 0.5f;
    } else {
        int i = a - 8000;
        src = p5 + ((size_t)b * 400 + i) * NCH;
        stride = 32.0f;
        int gyi = i / 20;
        gx = (float)(i - gyi * 20) + 0.5f;
        gy = (float)gyi + 0.5f;
    }

    const float4* s4 = (const float4*)src;

    // DFL: 4 softmax(16) -> expectation over bins 0..15
    float dist[4];
    #pragma unroll
    for (int g = 0; g < 4; ++g) {
        float v[16];
        #pragma unroll
        for (int q = 0; q < 4; ++q) {
            float4 t4 = s4[g * 4 + q];
            v[q * 4 + 0] = t4.x; v[q * 4 + 1] = t4.y;
            v[q * 4 + 2] = t4.z; v[q * 4 + 3] = t4.w;
        }
        float m = v[0];
        #pragma unroll
        for (int k = 1; k < 16; ++k) m = fmaxf(m, v[k]);
        float ssum = 0.0f, wsum = 0.0f;
        #pragma unroll
        for (int k = 0; k < 16; ++k) {
            float e = expf(v[k] - m);
            ssum += e;
            wsum += e * (float)k;
        }
        dist[g] = wsum / ssum;
    }

    // class: max + first-occurrence argmax over 80 logits
    float best = -INFINITY;
    int cbest = 0;
    #pragma unroll
    for (int q = 0; q < 20; ++q) {
        float4 t4 = s4[16 + q];
        int c = q * 4;
        if (t4.x > best) { best = t4.x; cbest = c + 0; }
        if (t4.y > best) { best = t4.y; cbest = c + 1; }
        if (t4.z > best) { best = t4.z; cbest = c + 2; }
        if (t4.w > best) { best = t4.w; cbest = c + 3; }
    }

    // dbox: xywh (matching reference op order), then xyxy for NMS
    float x1 = gx - dist[0], y1 = gy - dist[1];
    float x2 = gx + dist[2], y2 = gy + dist[3];
    float cx = ((x1 + x2) * 0.5f) * stride;
    float cy = ((y1 + y2) * 0.5f) * stride;
    float bw = (x2 - x1) * stride;
    float bh = (y2 - y1) * stride;
    float hx = bw * 0.5f, hy = bh * 0.5f;

    ((float4*)boxes)[t] = make_float4(cx - hx, cy - hy, cx + hx, cy + hy);

    float sig = 1.0f / (1.0f + expf(-best));
    scores[t] = (sig > CONF_THR) ? sig : 0.0f;
    clsArr[t] = cbest;
}

// ---------------------------------------------------------------------------
// Kernel 2: per-batch exact top-300 + greedy NMS + output write.
// One block (1024 threads) per batch image.
// ---------------------------------------------------------------------------
__global__ __launch_bounds__(1024) void nms_kernel(
    const float* __restrict__ boxes, const float* __restrict__ scores,
    const int* __restrict__ clsArr, float* __restrict__ out)
{
    __shared__ unsigned hist[NBINS];
    __shared__ unsigned long long cand[CAND_CAP];
    __shared__ float cbox[MAX_DET][4];
    __shared__ float obox[MAX_DET][4];
    __shared__ float tops[MAX_DET];
    __shared__ float tcls[MAX_DET];
    __shared__ unsigned mask[MAX_DET][MASK_W];
    __shared__ unsigned char keepA[MAX_DET];
    __shared__ int bstar, cnt;

    const int b = blockIdx.x;
    const int tid = threadIdx.x;
    const float* sc = scores + (size_t)b * A_TOT;
    const float* bx = boxes + (size_t)b * A_TOT * 4;
    const int* cl = clsArr + (size_t)b * A_TOT;

    // --- Phase A: histogram of scores (all in [0,1)) -----------------------
    if (tid < NBINS) hist[tid] = 0;
    if (tid == 0) cnt = 0;
    __syncthreads();
    for (int i = tid; i < A_TOT; i += 1024) {
        float s = sc[i];
        int bin = (int)(s * (float)NBINS);
        bin = min(bin, NBINS - 1);
        atomicAdd(&hist[bin], 1u);
    }
    __syncthreads();

    // suffix sum (Hillis-Steele): hist[t] = #scores with bin >= t
    for (int d = 1; d < NBINS; d <<= 1) {
        unsigned v = hist[tid];
        if (tid + d < NBINS) v += hist[tid + d];
        __syncthreads();
        hist[tid] = v;
        __syncthreads();
    }
    // b* = largest bin with suffix count >= MAX_DET  (exists: hist[0]=8400)
    if (hist[tid] >= MAX_DET && (tid == NBINS - 1 || hist[tid + 1] < MAX_DET))
        bstar = tid;
    __syncthreads();
    const int bs = bstar;

    // --- Phase B: compact candidates (key = score_bits<<32 | ~idx) ---------
    for (int i = tid; i < CAND_CAP; i += 1024) cand[i] = 0ULL;
    __syncthreads();
    for (int i = tid; i < A_TOT; i += 1024) {
        float s = sc[i];
        int bin = min((int)(s * (float)NBINS), NBINS - 1);
        if (bin >= bs) {
            int pos = atomicAdd(&cnt, 1);
            if (pos < CAND_CAP) {
                unsigned sb = __float_as_uint(s);
                cand[pos] = ((unsigned long long)sb << 32) |
                            (unsigned long long)(0xFFFFFFFFu - (unsigned)i);
            }
        }
    }
    __syncthreads();

    // --- Phase C: bitonic sort, descending (ties -> smaller idx first) -----
    for (int k = 2; k <= CAND_CAP; k <<= 1) {
        for (int j = k >> 1; j > 0; j >>= 1) {
            for (int i = tid; i < CAND_CAP; i += 1024) {
                int l = i ^ j;
                if (l > i) {
                    unsigned long long va = cand[i], vb = cand[l];
                    bool desc = ((i & k) == 0);
                    if (desc ? (va < vb) : (va > vb)) {
                        cand[i] = vb; cand[l] = va;
                    }
                }
            }
            __syncthreads();
        }
    }

    // --- Phase D: unpack top-300, gather boxes/cls, class-offset boxes -----
    if (tid < MAX_DET) {
        unsigned long long key = cand[tid];
        float s = __uint_as_float((unsigned)(key >> 32));
        unsigned idx = 0xFFFFFFFFu - (unsigned)(key & 0xFFFFFFFFull);
        tops[tid] = s;
        if (s > 0.0f && idx < A_TOT) {
            float4 bb = ((const float4*)bx)[idx];
            cbox[tid][0] = bb.x; cbox[tid][1] = bb.y;
            cbox[tid][2] = bb.z; cbox[tid][3] = bb.w;
            float cf = (float)cl[idx];
            tcls[tid] = cf;
            float off = cf * MAX_WH;
            obox[tid][0] = bb.x + off; obox[tid][1] = bb.y + off;
            obox[tid][2] = bb.z + off; obox[tid][3] = bb.w + off;
        } else {
            cbox[tid][0] = cbox[tid][1] = cbox[tid][2] = cbox[tid][3] = 0.0f;
            obox[tid][0] = obox[tid][1] = obox[tid][2] = obox[tid][3] = 0.0f;
            tcls[tid] = 0.0f;
        }
    }
    __syncthreads();

    // --- Phase E: 300x300 IoU > thr bitmask ---------------------------------
    for (int task = tid; task < MAX_DET * MASK_W; task += 1024) {
        int i = task / MASK_W, wq = task - (task / MASK_W) * MASK_W;
        float ax1 = obox[i][0], ay1 = obox[i][1];
        float ax2 = obox[i][2], ay2 = obox[i][3];
        float aa = (ax2 - ax1) * (ay2 - ay1);
        unsigned bits = 0;
        int j0 = wq * 32;
        #pragma unroll 4
        for (int jj = 0; jj < 32; ++jj) {
            int j = j0 + jj;
            if (j >= MAX_DET) break;
            float bx1 = obox[j][0], by1 = obox[j][1];
            float bx2 = obox[j][2], by2 = obox[j][3];
            float ab = (bx2 - bx1) * (by2 - by1);
            float lx = fmaxf(ax1, bx1), ly = fmaxf(ay1, by1);
            float rx = fminf(ax2, bx2), ry = fminf(ay2, by2);
            float iw = fmaxf(rx - lx, 0.0f), ih = fmaxf(ry - ly, 0.0f);
            float inter = iw * ih;
            float iou = inter / (aa + ab - inter + 1e-7f);
            if (iou > IOU_THR) bits |= (1u << jj);
        }
        mask[i][wq] = bits;
    }
    __syncthreads();

    // --- Phase F: greedy scan (wave 0; lane w owns suppressed-word w) -------
    if (tid < 64) {
        unsigned supp = 0u;
        for (int i = 0; i < MAX_DET; ++i) {
            float si = tops[i];
            unsigned sw = __shfl(supp, i >> 5, 64);
            bool suppressed = (sw >> (i & 31)) & 1u;
            bool ki = (si > 0.0f) && !suppressed;
            if (ki && tid < MASK_W) supp |= mask[i][tid];
            if (tid == 0) keepA[i] = ki ? 1 : 0;
        }
    }
    __syncthreads();

    // --- Phase G: write output [cbox(4), score, cls], zero if not kept ------
    float* ob = out + (size_t)b * MAX_DET * 6;
    for (int e = tid; e < MAX_DET * 6; e += 1024) {
        int i = e / 6, c = e - (e / 6) * 6;
        float val = 0.0f;
        if (keepA[i]) {
            if (c < 4)        val = cbox[i][c];
            else if (c == 4)  val = tops[i];
            else              val = tcls[i];
        }
        ob[e] = val;
    }
}

// ---------------------------------------------------------------------------
extern "C" void kernel_launch(void* const* d_in, const int* in_sizes, int n_in,
                              void* d_out, int out_size, void* d_ws, size_t ws_size,
                              hipStream_t stream) {
    const float* p3 = (const float*)d_in[0];
    const float* p4 = (const float*)d_in[1];
    const float* p5 = (const float*)d_in[2];
    float* out = (float*)d_out;

    float* boxes  = (float*)d_ws;                                  // B*A*4 f32
    float* scores = boxes + (size_t)BATCH * A_TOT * 4;             // B*A f32
    int*   cls    = (int*)(scores + (size_t)BATCH * A_TOT);        // B*A i32

    int total = BATCH * A_TOT;
    int blocks = (total + 255) / 256;
    decode_kernel<<<blocks, 256, 0, stream>>>(p3, p4, p5, boxes, scores, cls);
    nms_kernel<<<BATCH, 1024, 0, stream>>>(boxes, scores, cls, out);
}

// Round 2
// 98.145 us; speedup vs baseline: 1.2290x; 1.2290x over previous
//
#include <hip/hip_runtime.h>
#include <math.h>

#define NUM_CLASSES 80
#define REG_MAX 16
#define NCH 144            // 4*REG_MAX + NUM_CLASSES
#define A_TOT 8400         // 80*80 + 40*40 + 20*20
#define BATCH 32
#define MAX_DET 300
#define CONF_THR 0.25f
#define IOU_THR 0.7f
#define MAX_WH 7680.0f
#define CAND_CAP 512
#define NBINS 1024
#define MASK_W 10          // ceil(300/32)

// ---------------------------------------------------------------------------
// Kernel 1: decode. One thread per (batch, anchor). (unchanged from R1)
// ---------------------------------------------------------------------------
__global__ __launch_bounds__(256) void decode_kernel(
    const float* __restrict__ p3, const float* __restrict__ p4,
    const float* __restrict__ p5,
    float* __restrict__ boxes, float* __restrict__ scores,
    int* __restrict__ clsArr)
{
    int t = blockIdx.x * blockDim.x + threadIdx.x;
    if (t >= BATCH * A_TOT) return;
    int b = t / A_TOT;
    int a = t - b * A_TOT;

    const float* src;
    float stride, gx, gy;
    if (a < 6400) {
        src = p3 + ((size_t)b * 6400 + a) * NCH;
        stride = 8.0f;
        int gyi = a / 80;
        gx = (float)(a - gyi * 80) + 0.5f;
        gy = (float)gyi + 0.5f;
    } else if (a < 8000) {
        int i = a - 6400;
        src = p4 + ((size_t)b * 1600 + i) * NCH;
        stride = 16.0f;
        int gyi = i / 40;
        gx = (float)(i - gyi * 40) + 0.5f;
        gy = (float)gyi + 0.5f;
    } else {
        int i = a - 8000;
        src = p5 + ((size_t)b * 400 + i) * NCH;
        stride = 32.0f;
        int gyi = i / 20;
        gx = (float)(i - gyi * 20) + 0.5f;
        gy = (float)gyi + 0.5f;
    }

    const float4* s4 = (const float4*)src;

    // DFL: 4 softmax(16) -> expectation over bins 0..15
    float dist[4];
    #pragma unroll
    for (int g = 0; g < 4; ++g) {
        float v[16];
        #pragma unroll
        for (int q = 0; q < 4; ++q) {
            float4 t4 = s4[g * 4 + q];
            v[q * 4 + 0] = t4.x; v[q * 4 + 1] = t4.y;
            v[q * 4 + 2] = t4.z; v[q * 4 + 3] = t4.w;
        }
        float m = v[0];
        #pragma unroll
        for (int k = 1; k < 16; ++k) m = fmaxf(m, v[k]);
        float ssum = 0.0f, wsum = 0.0f;
        #pragma unroll
        for (int k = 0; k < 16; ++k) {
            float e = expf(v[k] - m);
            ssum += e;
            wsum += e * (float)k;
        }
        dist[g] = wsum / ssum;
    }

    // class: max + first-occurrence argmax over 80 logits
    float best = -INFINITY;
    int cbest = 0;
    #pragma unroll
    for (int q = 0; q < 20; ++q) {
        float4 t4 = s4[16 + q];
        int c = q * 4;
        if (t4.x > best) { best = t4.x; cbest = c + 0; }
        if (t4.y > best) { best = t4.y; cbest = c + 1; }
        if (t4.z > best) { best = t4.z; cbest = c + 2; }
        if (t4.w > best) { best = t4.w; cbest = c + 3; }
    }

    float x1 = gx - dist[0], y1 = gy - dist[1];
    float x2 = gx + dist[2], y2 = gy + dist[3];
    float cx = ((x1 + x2) * 0.5f) * stride;
    float cy = ((y1 + y2) * 0.5f) * stride;
    float bw = (x2 - x1) * stride;
    float bh = (y2 - y1) * stride;
    float hx = bw * 0.5f, hy = bh * 0.5f;

    ((float4*)boxes)[t] = make_float4(cx - hx, cy - hy, cx + hx, cy + hy);

    float sig = 1.0f / (1.0f + expf(-best));
    scores[t] = (sig > CONF_THR) ? sig : 0.0f;
    clsArr[t] = cbest;
}

// ---------------------------------------------------------------------------
// Kernel 2: per-batch exact top-300 + greedy NMS. One block (1024 thr)/batch.
// R2: bitonic sort -> rank-by-count (1 barrier); Hillis-Steele scan ->
// hierarchical wave-shuffle suffix scan (3 barriers); Phase E re-laid-out
// for broadcast reads + conflict-free mask writes.
// ---------------------------------------------------------------------------
__global__ __launch_bounds__(1024) void nms_kernel(
    const float* __restrict__ boxes, const float* __restrict__ scores,
    const int* __restrict__ clsArr, float* __restrict__ out)
{
    __shared__ unsigned hist[NBINS];
    __shared__ unsigned wtot[16];
    __shared__ unsigned woff[16];
    __shared__ unsigned long long cand[CAND_CAP];
    __shared__ unsigned long long sortedK[MAX_DET];
    __shared__ float4 cbox4[MAX_DET];
    __shared__ float4 obox4[MAX_DET];
    __shared__ float oarea[MAX_DET];
    __shared__ float tops[MAX_DET];
    __shared__ float tcls[MAX_DET];
    __shared__ unsigned mask[MASK_W][MAX_DET];
    __shared__ unsigned char keepA[MAX_DET];
    __shared__ int bstar, cnt;

    const int b = blockIdx.x;
    const int tid = threadIdx.x;
    const int lane = tid & 63;
    const int wv = tid >> 6;
    const float* sc = scores + (size_t)b * A_TOT;
    const float* bx = boxes + (size_t)b * A_TOT * 4;
    const int* cl = clsArr + (size_t)b * A_TOT;

    // --- prologue: zero-init ------------------------------------------------
    hist[tid] = 0;                          // 1024 threads == NBINS
    if (tid < CAND_CAP) cand[tid] = 0ULL;
    if (tid < MAX_DET) sortedK[tid] = 0ULL;
    if (tid == 0) cnt = 0;
    __syncthreads();

    // --- Phase A: histogram of scores (all in [0,1)) ------------------------
    for (int i = tid; i < A_TOT; i += 1024) {
        float s = sc[i];
        int bin = min((int)(s * (float)NBINS), NBINS - 1);
        atomicAdd(&hist[bin], 1u);
    }
    __syncthreads();

    // --- suffix scan: per-wave shuffle scan, then 16 wave totals ------------
    unsigned v = hist[tid];
    #pragma unroll
    for (int d = 1; d < 64; d <<= 1) {
        unsigned o = __shfl_down(v, d, 64);
        if (lane + d < 64) v += o;
    }
    if (lane == 0) wtot[wv] = v;            // wave-inclusive total
    __syncthreads();
    if (tid < 16) {
        unsigned u = wtot[tid];
        unsigned t2 = u;
        #pragma unroll
        for (int d = 1; d < 16; d <<= 1) {
            unsigned o = __shfl_down(t2, d, 64);
            if (tid + d < 16) t2 += o;
        }
        woff[tid] = t2 - u;                 // exclusive suffix (waves above)
    }
    __syncthreads();
    unsigned suff = v + woff[wv];
    hist[tid] = suff;                       // hist[t] = #scores with bin >= t
    __syncthreads();

    // b* = largest bin with suffix count >= MAX_DET (exists: hist[0]=8400)
    if (hist[tid] >= MAX_DET && (tid == NBINS - 1 || hist[tid + 1] < MAX_DET))
        bstar = tid;
    __syncthreads();
    const int bs = bstar;

    // --- Phase B: compact candidates (key = score_bits<<32 | ~idx) ----------
    for (int i = tid; i < A_TOT; i += 1024) {
        float s = sc[i];
        if (s > 0.0f) {
            int bin = min((int)(s * (float)NBINS), NBINS - 1);
            if (bin >= bs) {
                int pos = atomicAdd(&cnt, 1);
                if (pos < CAND_CAP) {
                    unsigned sb = __float_as_uint(s);
                    cand[pos] = ((unsigned long long)sb << 32) |
                                (unsigned long long)(0xFFFFFFFFu - (unsigned)i);
                }
            }
        }
    }
    __syncthreads();

    // --- Phase C: rank-by-count (exact lax.top_k order, unique keys) --------
    const int n = min(cnt, CAND_CAP);
    if (tid < CAND_CAP) {
        unsigned long long mykey = cand[tid];
        if (mykey != 0ULL) {
            int r = 0;
            #pragma unroll 8
            for (int j = 0; j < n; ++j) r += (cand[j] > mykey) ? 1 : 0;
            if (r < MAX_DET) sortedK[r] = mykey;
        }
    }
    __syncthreads();

    // --- Phase D: unpack top-300, gather boxes/cls, class-offset boxes ------
    if (tid < MAX_DET) {
        unsigned long long key = sortedK[tid];
        float s = __uint_as_float((unsigned)(key >> 32));
        unsigned idx = 0xFFFFFFFFu - (unsigned)(key & 0xFFFFFFFFull);
        tops[tid] = s;
        float4 bb = make_float4(0.f, 0.f, 0.f, 0.f);
        float4 ob = bb;
        float cf = 0.0f;
        if (key != 0ULL) {
            bb = ((const float4*)bx)[idx];
            cf = (float)cl[idx];
            float off = cf * MAX_WH;
            ob = make_float4(bb.x + off, bb.y + off, bb.z + off, bb.w + off);
        }
        cbox4[tid] = bb;
        obox4[tid] = ob;
        tcls[tid] = cf;
        oarea[tid] = (ob.z - ob.x) * (ob.w - ob.y);
    }
    __syncthreads();

    // --- Phase E: 300x300 IoU > thr bitmask ----------------------------------
    // task = w*300 + i: consecutive lanes -> consecutive i (b128-friendly);
    // inner j is wave-uniform -> broadcast reads, no conflicts.
    for (int task = tid; task < MASK_W * MAX_DET; task += 1024) {
        int w = task / MAX_DET;
        int i = task - w * MAX_DET;
        float4 a = obox4[i];
        float aa = oarea[i];
        unsigned bits = 0;
        int j0 = w * 32;
        int jend = min(32, MAX_DET - j0);
        for (int jj = 0; jj < jend; ++jj) {
            int j = j0 + jj;
            float4 bo = obox4[j];           // broadcast
            float ab = oarea[j];            // broadcast
            float lx = fmaxf(a.x, bo.x), ly = fmaxf(a.y, bo.y);
            float rx = fminf(a.z, bo.z), ry = fminf(a.w, bo.w);
            float iw = fmaxf(rx - lx, 0.0f), ih = fmaxf(ry - ly, 0.0f);
            float inter = iw * ih;
            float iou = inter / (aa + ab - inter + 1e-7f);
            if (iou > IOU_THR) bits |= (1u << jj);
        }
        mask[w][i] = bits;
    }
    __syncthreads();

    // --- Phase F: greedy scan (wave 0; lane w owns suppressed-word w) -------
    if (tid < 64) {
        unsigned supp = 0u;
        for (int i = 0; i < MAX_DET; ++i) {
            unsigned sw = __shfl(supp, i >> 5, 64);
            bool suppressed = (sw >> (i & 31)) & 1u;
            bool ki = (tops[i] > 0.0f) && !suppressed;
            if (ki && tid < MASK_W) supp |= mask[tid][i];
            if (tid == 0) keepA[i] = ki ? 1 : 0;
        }
    }
    __syncthreads();

    // --- Phase G: write output [cbox(4), score, cls], zero if not kept ------
    float* ob = out + (size_t)b * MAX_DET * 6;
    for (int e = tid; e < MAX_DET * 6; e += 1024) {
        int i = e / 6, c = e - (e / 6) * 6;
        float val = 0.0f;
        if (keepA[i]) {
            if (c < 4)        val = (&cbox4[i].x)[c];
            else if (c == 4)  val = tops[i];
            else              val = tcls[i];
        }
        ob[e] = val;
    }
}

// ---------------------------------------------------------------------------
extern "C" void kernel_launch(void* const* d_in, const int* in_sizes, int n_in,
                              void* d_out, int out_size, void* d_ws, size_t ws_size,
                              hipStream_t stream) {
    const float* p3 = (const float*)d_in[0];
    const float* p4 = (const float*)d_in[1];
    const float* p5 = (const float*)d_in[2];
    float* out = (float*)d_out;

    float* boxes  = (float*)d_ws;                                  // B*A*4 f32
    float* scores = boxes + (size_t)BATCH * A_TOT * 4;             // B*A f32
    int*   cls    = (int*)(scores + (size_t)BATCH * A_TOT);        // B*A i32

    int total = BATCH * A_TOT;
    int blocks = (total + 255) / 256;
    decode_kernel<<<blocks, 256, 0, stream>>>(p3, p4, p5, boxes, scores, cls);
    nms_kernel<<<BATCH, 1024, 0, stream>>>(boxes, scores, cls, out);
}

// Round 3
// 95.511 us; speedup vs baseline: 1.2629x; 1.0276x over previous
//
#include <hip/hip_runtime.h>
#include <math.h>

#define NUM_CLASSES 80
#define REG_MAX 16
#define NCH 144            // 4*REG_MAX + NUM_CLASSES
#define A_TOT 8400         // 80*80 + 40*40 + 20*20
#define BATCH 32
#define MAX_DET 300
#define CONF_THR 0.25f
#define IOU_THR 0.7f
#define MAX_WH 7680.0f
#define CAND_CAP 512
#define NBINS 1024
#define MASK_W 10          // ceil(300/32)

// ---------------------------------------------------------------------------
// Kernel 1 (R3): decode, LDS-staged + coalesced.
// Block = 256 threads, 64 anchors. Stage 64x144 floats (36 KB) with
// coalesced float4 loads; compute with 4 threads/anchor (one DFL softmax +
// 20 class logits each), merge via shuffles.
// Grid: L0 32*100 | L1 32*25 | L2 32*7 (tail chunk = 16 anchors).
// ---------------------------------------------------------------------------
__global__ __launch_bounds__(256) void decode_kernel(
    const float* __restrict__ p3, const float* __restrict__ p4,
    const float* __restrict__ p5,
    float* __restrict__ boxes, float* __restrict__ scores,
    int* __restrict__ clsArr)
{
    __shared__ float4 tile[64][37];        // pad: 148-dword row stride, <=2-way

    const int bid = blockIdx.x;
    const int tid = threadIdx.x;

    int level, b, chunk;
    if (bid < 3200)      { level = 0; b = bid / 100;  chunk = bid - b * 100; }
    else if (bid < 4000) { int r = bid - 3200; level = 1; b = r / 25; chunk = r - b * 25; }
    else                 { int r = bid - 4000; level = 2; b = r / 7;  chunk = r - b * 7;  }

    const float* lp; int hw, lbase; float strd;
    if (level == 0)      { lp = p3; hw = 6400; lbase = 0;    strd = 8.0f;  }
    else if (level == 1) { lp = p4; hw = 1600; lbase = 6400; strd = 16.0f; }
    else                 { lp = p5; hw = 400;  lbase = 8000; strd = 32.0f; }

    const int a0 = chunk * 64;             // first local anchor of this block
    const int nAnch = min(64, hw - a0);
    const int f4count = nAnch * 36;

    // --- stage: coalesced global -> LDS ------------------------------------
    const float4* g = (const float4*)lp + ((size_t)b * hw + a0) * 36;
    for (int f = tid; f < f4count; f += 256) {
        int a = f / 36;                    // const divisor
        int col = f - a * 36;
        tile[a][col] = g[f];
    }
    __syncthreads();

    // --- compute: 4 threads per anchor -------------------------------------
    const int a = tid >> 2;
    const int p = tid & 3;
    const int lane = tid & 63;
    const int gbase = lane & ~3;           // lane of p==0 in this group

    // DFL softmax for group p (16 channels)
    float v[16];
    {
        float4 r0 = tile[a][p * 4 + 0];
        float4 r1 = tile[a][p * 4 + 1];
        float4 r2 = tile[a][p * 4 + 2];
        float4 r3 = tile[a][p * 4 + 3];
        v[0]=r0.x; v[1]=r0.y; v[2]=r0.z; v[3]=r0.w;
        v[4]=r1.x; v[5]=r1.y; v[6]=r1.z; v[7]=r1.w;
        v[8]=r2.x; v[9]=r2.y; v[10]=r2.z; v[11]=r2.w;
        v[12]=r3.x; v[13]=r3.y; v[14]=r3.z; v[15]=r3.w;
    }
    float m = v[0];
    #pragma unroll
    for (int k = 1; k < 16; ++k) m = fmaxf(m, v[k]);
    float ssum = 0.0f, wsum = 0.0f;
    #pragma unroll
    for (int k = 0; k < 16; ++k) {
        float e = expf(v[k] - m);
        ssum += e;
        wsum += e * (float)k;
    }
    float distp = wsum / ssum;

    // classes p*20 .. p*20+19 (first-occurrence local argmax)
    float best = -INFINITY;
    int cbest = p * 20;
    #pragma unroll
    for (int q = 0; q < 5; ++q) {
        float4 c4 = tile[a][16 + p * 5 + q];
        int c = p * 20 + q * 4;
        if (c4.x > best) { best = c4.x; cbest = c + 0; }
        if (c4.y > best) { best = c4.y; cbest = c + 1; }
        if (c4.z > best) { best = c4.z; cbest = c + 2; }
        if (c4.w > best) { best = c4.w; cbest = c + 3; }
    }
    // merge across the 4-lane group; ties -> lower class idx (first occur.)
    #pragma unroll
    for (int d = 1; d < 4; d <<= 1) {
        float ob = __shfl_xor(best, d, 64);
        int   oc = __shfl_xor(cbest, d, 64);
        if (ob > best || (ob == best && oc < cbest)) { best = ob; cbest = oc; }
    }

    // gather the 4 dists
    float d0 = __shfl(distp, gbase + 0, 64);
    float d1 = __shfl(distp, gbase + 1, 64);
    float d2 = __shfl(distp, gbase + 2, 64);
    float d3 = __shfl(distp, gbase + 3, 64);

    if (a < nAnch) {
        int i = a0 + a;                    // local anchor index in level
        int gyi;
        if (level == 0)      gyi = i / 80;
        else if (level == 1) gyi = i / 40;
        else                 gyi = i / 20;
        int w = (level == 0) ? 80 : (level == 1) ? 40 : 20;
        float gx = (float)(i - gyi * w) + 0.5f;
        float gy = (float)gyi + 0.5f;

        float x1 = gx - d0, y1 = gy - d1;
        float x2 = gx + d2, y2 = gy + d3;
        float cx = ((x1 + x2) * 0.5f) * strd;
        float cy = ((y1 + y2) * 0.5f) * strd;
        float bw = (x2 - x1) * strd;
        float bh = (y2 - y1) * strd;
        float hx = bw * 0.5f, hy = bh * 0.5f;

        size_t t = (size_t)b * A_TOT + lbase + i;
        if (p == 0) {
            ((float4*)boxes)[t] = make_float4(cx - hx, cy - hy, cx + hx, cy + hy);
        } else if (p == 1) {
            float sig = 1.0f / (1.0f + expf(-best));
            scores[t] = (sig > CONF_THR) ? sig : 0.0f;
        } else if (p == 2) {
            clsArr[t] = cbest;
        }
    }
}

// ---------------------------------------------------------------------------
// Kernel 2: per-batch exact top-300 + greedy NMS. One block (1024 thr)/batch.
// (unchanged from R2)
// ---------------------------------------------------------------------------
__global__ __launch_bounds__(1024) void nms_kernel(
    const float* __restrict__ boxes, const float* __restrict__ scores,
    const int* __restrict__ clsArr, float* __restrict__ out)
{
    __shared__ unsigned hist[NBINS];
    __shared__ unsigned wtot[16];
    __shared__ unsigned woff[16];
    __shared__ unsigned long long cand[CAND_CAP];
    __shared__ unsigned long long sortedK[MAX_DET];
    __shared__ float4 cbox4[MAX_DET];
    __shared__ float4 obox4[MAX_DET];
    __shared__ float oarea[MAX_DET];
    __shared__ float tops[MAX_DET];
    __shared__ float tcls[MAX_DET];
    __shared__ unsigned mask[MASK_W][MAX_DET];
    __shared__ unsigned char keepA[MAX_DET];
    __shared__ int bstar, cnt;

    const int b = blockIdx.x;
    const int tid = threadIdx.x;
    const int lane = tid & 63;
    const int wv = tid >> 6;
    const float* sc = scores + (size_t)b * A_TOT;
    const float* bx = boxes + (size_t)b * A_TOT * 4;
    const int* cl = clsArr + (size_t)b * A_TOT;

    hist[tid] = 0;
    if (tid < CAND_CAP) cand[tid] = 0ULL;
    if (tid < MAX_DET) sortedK[tid] = 0ULL;
    if (tid == 0) cnt = 0;
    __syncthreads();

    for (int i = tid; i < A_TOT; i += 1024) {
        float s = sc[i];
        int bin = min((int)(s * (float)NBINS), NBINS - 1);
        atomicAdd(&hist[bin], 1u);
    }
    __syncthreads();

    unsigned v = hist[tid];
    #pragma unroll
    for (int d = 1; d < 64; d <<= 1) {
        unsigned o = __shfl_down(v, d, 64);
        if (lane + d < 64) v += o;
    }
    if (lane == 0) wtot[wv] = v;
    __syncthreads();
    if (tid < 16) {
        unsigned u = wtot[tid];
        unsigned t2 = u;
        #pragma unroll
        for (int d = 1; d < 16; d <<= 1) {
            unsigned o = __shfl_down(t2, d, 64);
            if (tid + d < 16) t2 += o;
        }
        woff[tid] = t2 - u;
    }
    __syncthreads();
    unsigned suff = v + woff[wv];
    hist[tid] = suff;
    __syncthreads();

    if (hist[tid] >= MAX_DET && (tid == NBINS - 1 || hist[tid + 1] < MAX_DET))
        bstar = tid;
    __syncthreads();
    const int bs = bstar;

    for (int i = tid; i < A_TOT; i += 1024) {
        float s = sc[i];
        if (s > 0.0f) {
            int bin = min((int)(s * (float)NBINS), NBINS - 1);
            if (bin >= bs) {
                int pos = atomicAdd(&cnt, 1);
                if (pos < CAND_CAP) {
                    unsigned sb = __float_as_uint(s);
                    cand[pos] = ((unsigned long long)sb << 32) |
                                (unsigned long long)(0xFFFFFFFFu - (unsigned)i);
                }
            }
        }
    }
    __syncthreads();

    const int n = min(cnt, CAND_CAP);
    if (tid < CAND_CAP) {
        unsigned long long mykey = cand[tid];
        if (mykey != 0ULL) {
            int r = 0;
            #pragma unroll 8
            for (int j = 0; j < n; ++j) r += (cand[j] > mykey) ? 1 : 0;
            if (r < MAX_DET) sortedK[r] = mykey;
        }
    }
    __syncthreads();

    if (tid < MAX_DET) {
        unsigned long long key = sortedK[tid];
        float s = __uint_as_float((unsigned)(key >> 32));
        unsigned idx = 0xFFFFFFFFu - (unsigned)(key & 0xFFFFFFFFull);
        tops[tid] = s;
        float4 bb = make_float4(0.f, 0.f, 0.f, 0.f);
        float4 ob = bb;
        float cf = 0.0f;
        if (key != 0ULL) {
            bb = ((const float4*)bx)[idx];
            cf = (float)cl[idx];
            float off = cf * MAX_WH;
            ob = make_float4(bb.x + off, bb.y + off, bb.z + off, bb.w + off);
        }
        cbox4[tid] = bb;
        obox4[tid] = ob;
        tcls[tid] = cf;
        oarea[tid] = (ob.z - ob.x) * (ob.w - ob.y);
    }
    __syncthreads();

    for (int task = tid; task < MASK_W * MAX_DET; task += 1024) {
        int w = task / MAX_DET;
        int i = task - w * MAX_DET;
        float4 a = obox4[i];
        float aa = oarea[i];
        unsigned bits = 0;
        int j0 = w * 32;
        int jend = min(32, MAX_DET - j0);
        for (int jj = 0; jj < jend; ++jj) {
            int j = j0 + jj;
            float4 bo = obox4[j];
            float ab = oarea[j];
            float lx = fmaxf(a.x, bo.x), ly = fmaxf(a.y, bo.y);
            float rx = fminf(a.z, bo.z), ry = fminf(a.w, bo.w);
            float iw = fmaxf(rx - lx, 0.0f), ih = fmaxf(ry - ly, 0.0f);
            float inter = iw * ih;
            float iou = inter / (aa + ab - inter + 1e-7f);
            if (iou > IOU_THR) bits |= (1u << jj);
        }
        mask[w][i] = bits;
    }
    __syncthreads();

    if (tid < 64) {
        unsigned supp = 0u;
        for (int i = 0; i < MAX_DET; ++i) {
            unsigned sw = __shfl(supp, i >> 5, 64);
            bool suppressed = (sw >> (i & 31)) & 1u;
            bool ki = (tops[i] > 0.0f) && !suppressed;
            if (ki && tid < MASK_W) supp |= mask[tid][i];
            if (tid == 0) keepA[i] = ki ? 1 : 0;
        }
    }
    __syncthreads();

    float* ob = out + (size_t)b * MAX_DET * 6;
    for (int e = tid; e < MAX_DET * 6; e += 1024) {
        int i = e / 6, c = e - (e / 6) * 6;
        float val = 0.0f;
        if (keepA[i]) {
            if (c < 4)        val = (&cbox4[i].x)[c];
            else if (c == 4)  val = tops[i];
            else              val = tcls[i];
        }
        ob[e] = val;
    }
}

// ---------------------------------------------------------------------------
extern "C" void kernel_launch(void* const* d_in, const int* in_sizes, int n_in,
                              void* d_out, int out_size, void* d_ws, size_t ws_size,
                              hipStream_t stream) {
    const float* p3 = (const float*)d_in[0];
    const float* p4 = (const float*)d_in[1];
    const float* p5 = (const float*)d_in[2];
    float* out = (float*)d_out;

    float* boxes  = (float*)d_ws;                                  // B*A*4 f32
    float* scores = boxes + (size_t)BATCH * A_TOT * 4;             // B*A f32
    int*   cls    = (int*)(scores + (size_t)BATCH * A_TOT);        // B*A i32

    int blocks = 3200 + 800 + 224;         // L0 + L1 + L2 chunks
    decode_kernel<<<blocks, 256, 0, stream>>>(p3, p4, p5, boxes, scores, cls);
    nms_kernel<<<BATCH, 1024, 0, stream>>>(boxes, scores, cls, out);
}

// Round 4
// 83.398 us; speedup vs baseline: 1.4464x; 1.1452x over previous
//
#include <hip/hip_runtime.h>
#include <math.h>

#define NUM_CLASSES 80
#define REG_MAX 16
#define NCH 144            // 4*REG_MAX + NUM_CLASSES
#define A_TOT 8400         // 80*80 + 40*40 + 20*20
#define BATCH 32
#define MAX_DET 300
#define CONF_THR 0.25f
#define IOU_THR 0.7f
#define MAX_WH 7680.0f
#define CAND_CAP 512
#define NBINS 1024
#define MASK_W 10          // ceil(300/32)

// ---------------------------------------------------------------------------
// Kernel 1 (R4): scores + argmax class ONLY (class channels 64..143).
// 4 threads per anchor; lane-group p reads float4 col 16+4q+p so each load
// instruction covers contiguous 64B lines (full coalescing). Thread p owns
// classes {16q+4p..+3}, visited in ascending order; merge = (max, min idx)
// == exact global first-occurrence argmax.
// Grid: 4200 blocks x 256 = 32*8400*4 threads exactly.
// ---------------------------------------------------------------------------
__global__ __launch_bounds__(256) void score_kernel(
    const float* __restrict__ p3, const float* __restrict__ p4,
    const float* __restrict__ p5,
    float* __restrict__ scores, int* __restrict__ clsArr)
{
    const int t = blockIdx.x * 256 + threadIdx.x;
    const int g = t >> 2;                  // anchor id in [0, 268800)
    const int p = t & 3;
    const int lane = threadIdx.x & 63;
    const int b = g / A_TOT;
    const int a = g - b * A_TOT;

    const float* src;
    if (a < 6400)      src = p3 + ((size_t)b * 6400 + a) * NCH;
    else if (a < 8000) src = p4 + ((size_t)b * 1600 + (a - 6400)) * NCH;
    else               src = p5 + ((size_t)b * 400  + (a - 8000)) * NCH;

    const float4* s4 = (const float4*)src;
    float best = -INFINITY;
    int cbest = p * 4;                     // first class this thread visits
    #pragma unroll
    for (int q = 0; q < 5; ++q) {
        float4 c4 = s4[16 + q * 4 + p];    // coalesced: p spans one 64B line
        int c = q * 16 + p * 4;            // class index of c4.x
        if (c4.x > best) { best = c4.x; cbest = c + 0; }
        if (c4.y > best) { best = c4.y; cbest = c + 1; }
        if (c4.z > best) { best = c4.z; cbest = c + 2; }
        if (c4.w > best) { best = c4.w; cbest = c + 3; }
    }
    // merge across 4-lane group; ties -> lower class idx (first occurrence)
    #pragma unroll
    for (int d = 1; d < 4; d <<= 1) {
        float ob = __shfl_xor(best, d, 64);
        int   oc = __shfl_xor(cbest, d, 64);
        if (ob > best || (ob == best && oc < cbest)) { best = ob; cbest = oc; }
    }

    if (p == 0) {
        float sig = 1.0f / (1.0f + expf(-best));
        scores[g] = (sig > CONF_THR) ? sig : 0.0f;
        clsArr[g] = cbest;
    }
}

// ---------------------------------------------------------------------------
// Kernel 2 (R4): per-batch top-300 select + DFL box decode (survivors only)
// + IoU mask + greedy NMS + write. One block (1024 thr) per batch.
// ---------------------------------------------------------------------------
__global__ __launch_bounds__(1024) void nms_kernel(
    const float* __restrict__ p3, const float* __restrict__ p4,
    const float* __restrict__ p5,
    const float* __restrict__ scores, const int* __restrict__ clsArr,
    float* __restrict__ out)
{
    __shared__ unsigned hist[NBINS];
    __shared__ unsigned wtot[16];
    __shared__ unsigned woff[16];
    __shared__ unsigned long long cand[CAND_CAP];
    __shared__ unsigned long long sortedK[MAX_DET];
    __shared__ float4 cbox4[MAX_DET];
    __shared__ float4 obox4[MAX_DET];
    __shared__ float oarea[MAX_DET];
    __shared__ float tops[MAX_DET];
    __shared__ float tcls[MAX_DET];
    __shared__ unsigned mask[MASK_W][MAX_DET];
    __shared__ unsigned char keepA[MAX_DET];
    __shared__ int bstar, cnt;

    const int b = blockIdx.x;
    const int tid = threadIdx.x;
    const int lane = tid & 63;
    const int wv = tid >> 6;
    const float* sc = scores + (size_t)b * A_TOT;
    const int* cl = clsArr + (size_t)b * A_TOT;

    // --- prologue -----------------------------------------------------------
    hist[tid] = 0;
    if (tid < CAND_CAP) cand[tid] = 0ULL;
    if (tid < MAX_DET) sortedK[tid] = 0ULL;
    if (tid == 0) { cnt = 0; bstar = 0; }
    __syncthreads();

    // --- Phase A: load scores to regs once; histogram of NONZERO scores -----
    float sreg[9];
    int breg[9];
    #pragma unroll
    for (int k = 0; k < 9; ++k) {
        int i = tid + k * 1024;
        float s = (i < A_TOT) ? sc[i] : 0.0f;
        sreg[k] = s;
        if (s > 0.0f) {
            int bin = min((int)(s * (float)NBINS), NBINS - 1);
            breg[k] = bin;
            atomicAdd(&hist[bin], 1u);
        } else breg[k] = -1;
    }
    __syncthreads();

    // --- suffix scan: per-wave shuffle scan, then 16 wave totals ------------
    unsigned v = hist[tid];
    #pragma unroll
    for (int d = 1; d < 64; d <<= 1) {
        unsigned o = __shfl_down(v, d, 64);
        if (lane + d < 64) v += o;
    }
    if (lane == 0) wtot[wv] = v;
    __syncthreads();
    if (tid < 16) {
        unsigned u = wtot[tid];
        unsigned t2 = u;
        #pragma unroll
        for (int d = 1; d < 16; d <<= 1) {
            unsigned o = __shfl_down(t2, d, 64);
            if (tid + d < 16) t2 += o;
        }
        woff[tid] = t2 - u;
    }
    __syncthreads();
    unsigned suff = v + woff[wv];
    hist[tid] = suff;                      // hist[t] = #nonzero with bin >= t
    __syncthreads();

    // b* = largest bin with suffix >= MAX_DET; if none (few positives) bs=0
    if (hist[tid] >= MAX_DET && (tid == NBINS - 1 || hist[tid + 1] < MAX_DET))
        bstar = tid;
    __syncthreads();
    const int bs = bstar;

    // --- Phase B: compact candidates from registers -------------------------
    #pragma unroll
    for (int k = 0; k < 9; ++k) {
        if (breg[k] >= bs && breg[k] >= 0) {
            int i = tid + k * 1024;
            int pos = atomicAdd(&cnt, 1);
            if (pos < CAND_CAP) {
                unsigned sb = __float_as_uint(sreg[k]);
                cand[pos] = ((unsigned long long)sb << 32) |
                            (unsigned long long)(0xFFFFFFFFu - (unsigned)i);
            }
        }
    }
    __syncthreads();

    // --- Phase C: rank-by-count (exact lax.top_k order, unique keys) --------
    const int n = min(cnt, CAND_CAP);
    if (tid < CAND_CAP) {
        unsigned long long mykey = cand[tid];
        if (mykey != 0ULL) {
            int r = 0;
            #pragma unroll 8
            for (int j = 0; j < n; ++j) r += (cand[j] > mykey) ? 1 : 0;
            if (r < MAX_DET) sortedK[r] = mykey;
        }
    }
    __syncthreads();

    // --- Phase D: unpack + DFL box decode for survivors (4 thr/anchor) ------
    const int gbase = lane & ~3;
    #pragma unroll
    for (int sweep = 0; sweep < 2; ++sweep) {
        int det = sweep * 256 + (tid >> 2);
        int p = tid & 3;
        unsigned long long key = (det < MAX_DET) ? sortedK[det] : 0ULL;
        float distp = 0.0f;
        unsigned i = 0xFFFFFFFFu - (unsigned)(key & 0xFFFFFFFFull);

        if (key != 0ULL) {
            const float* rowp;
            if (i < 6400)      rowp = p3 + ((size_t)b * 6400 + i) * NCH;
            else if (i < 8000) rowp = p4 + ((size_t)b * 1600 + (i - 6400)) * NCH;
            else               rowp = p5 + ((size_t)b * 400  + (i - 8000)) * NCH;
            const float4* s4 = (const float4*)rowp;
            float vv[16];
            float4 r0 = s4[p * 4 + 0];
            float4 r1 = s4[p * 4 + 1];
            float4 r2 = s4[p * 4 + 2];
            float4 r3 = s4[p * 4 + 3];
            vv[0]=r0.x; vv[1]=r0.y; vv[2]=r0.z; vv[3]=r0.w;
            vv[4]=r1.x; vv[5]=r1.y; vv[6]=r1.z; vv[7]=r1.w;
            vv[8]=r2.x; vv[9]=r2.y; vv[10]=r2.z; vv[11]=r2.w;
            vv[12]=r3.x; vv[13]=r3.y; vv[14]=r3.z; vv[15]=r3.w;
            float m = vv[0];
            #pragma unroll
            for (int k = 1; k < 16; ++k) m = fmaxf(m, vv[k]);
            float ssum = 0.0f, wsum = 0.0f;
            #pragma unroll
            for (int k = 0; k < 16; ++k) {
                float e = expf(vv[k] - m);
                ssum += e;
                wsum += e * (float)k;
            }
            distp = wsum / ssum;
        }
        // group-uniform divergence: shuffles safe
        float d0 = __shfl(distp, gbase + 0, 64);
        float d1 = __shfl(distp, gbase + 1, 64);
        float d2 = __shfl(distp, gbase + 2, 64);
        float d3 = __shfl(distp, gbase + 3, 64);

        if (det < MAX_DET && p == 0) {
            float s = __uint_as_float((unsigned)(key >> 32));
            tops[det] = s;
            float4 bb = make_float4(0.f, 0.f, 0.f, 0.f);
            float4 ob = bb;
            float cf = 0.0f;
            if (key != 0ULL) {
                int gyi, gxi; float strd;
                if (i < 6400)      { gyi = i / 80; gxi = i - gyi * 80; strd = 8.0f; }
                else if (i < 8000) { int li = i - 6400; gyi = li / 40; gxi = li - gyi * 40; strd = 16.0f; }
                else               { int li = i - 8000; gyi = li / 20; gxi = li - gyi * 20; strd = 32.0f; }
                float gx = (float)gxi + 0.5f;
                float gy = (float)gyi + 0.5f;
                float x1 = gx - d0, y1 = gy - d1;
                float x2 = gx + d2, y2 = gy + d3;
                float cx = ((x1 + x2) * 0.5f) * strd;
                float cy = ((y1 + y2) * 0.5f) * strd;
                float bw = (x2 - x1) * strd;
                float bh = (y2 - y1) * strd;
                float hx = bw * 0.5f, hy = bh * 0.5f;
                bb = make_float4(cx - hx, cy - hy, cx + hx, cy + hy);
                cf = (float)cl[i];
                float off = cf * MAX_WH;
                ob = make_float4(bb.x + off, bb.y + off, bb.z + off, bb.w + off);
            }
            cbox4[det] = bb;
            obox4[det] = ob;
            tcls[det] = cf;
            oarea[det] = (ob.z - ob.x) * (ob.w - ob.y);
        }
    }
    __syncthreads();

    // --- Phase E: 300x300 IoU > thr bitmask ---------------------------------
    for (int task = tid; task < MASK_W * MAX_DET; task += 1024) {
        int w = task / MAX_DET;
        int i = task - w * MAX_DET;
        float4 a = obox4[i];
        float aa = oarea[i];
        unsigned bits = 0;
        int j0 = w * 32;
        int jend = min(32, MAX_DET - j0);
        for (int jj = 0; jj < jend; ++jj) {
            int j = j0 + jj;
            float4 bo = obox4[j];
            float ab = oarea[j];
            float lx = fmaxf(a.x, bo.x), ly = fmaxf(a.y, bo.y);
            float rx = fminf(a.z, bo.z), ry = fminf(a.w, bo.w);
            float iw = fmaxf(rx - lx, 0.0f), ih = fmaxf(ry - ly, 0.0f);
            float inter = iw * ih;
            float iou = inter / (aa + ab - inter + 1e-7f);
            if (iou > IOU_THR) bits |= (1u << jj);
        }
        mask[w][i] = bits;
    }
    __syncthreads();

    // --- Phase F: greedy scan (wave 0; lane w owns suppressed-word w) -------
    if (tid < 64) {
        unsigned supp = 0u;
        for (int i = 0; i < MAX_DET; ++i) {
            unsigned sw = __shfl(supp, i >> 5, 64);
            bool suppressed = (sw >> (i & 31)) & 1u;
            bool ki = (tops[i] > 0.0f) && !suppressed;
            if (ki && tid < MASK_W) supp |= mask[tid][i];
            if (tid == 0) keepA[i] = ki ? 1 : 0;
        }
    }
    __syncthreads();

    // --- Phase G: write output [cbox(4), score, cls], zero if not kept ------
    float* ob = out + (size_t)b * MAX_DET * 6;
    for (int e = tid; e < MAX_DET * 6; e += 1024) {
        int i = e / 6, c = e - (e / 6) * 6;
        float val = 0.0f;
        if (keepA[i]) {
            if (c < 4)        val = (&cbox4[i].x)[c];
            else if (c == 4)  val = tops[i];
            else              val = tcls[i];
        }
        ob[e] = val;
    }
}

// ---------------------------------------------------------------------------
extern "C" void kernel_launch(void* const* d_in, const int* in_sizes, int n_in,
                              void* d_out, int out_size, void* d_ws, size_t ws_size,
                              hipStream_t stream) {
    const float* p3 = (const float*)d_in[0];
    const float* p4 = (const float*)d_in[1];
    const float* p5 = (const float*)d_in[2];
    float* out = (float*)d_out;

    float* scores = (float*)d_ws;                                  // B*A f32
    int*   cls    = (int*)(scores + (size_t)BATCH * A_TOT);        // B*A i32

    score_kernel<<<4200, 256, 0, stream>>>(p3, p4, p5, scores, cls);
    nms_kernel<<<BATCH, 1024, 0, stream>>>(p3, p4, p5, scores, cls, out);
}